// Round 5
// baseline (287.263 us; speedup 1.0000x reference)
//
#include <hip/hip_runtime.h>
#include <hip/hip_bf16.h>

#define NQ 12
typedef __hip_bfloat16 bf16;
typedef float v2f __attribute__((ext_vector_type(2)));

__device__ __forceinline__ float b2f(unsigned int u) {
  union { unsigned int i; float f; } v; v.i = u << 16; return v.f;
}

// Dtype-adaptive scalar load (world: f32 — probe-verified on HW R5..R19).
__device__ __forceinline__ float ldv(const void* p, int i, bool f32) {
  if (f32) return ((const float*)p)[i];
  return b2f((unsigned int)((const unsigned short*)p)[i]);
}

// Composite permutation of the 12 sequential ring CNOTs. HW-verified (R2..R19).
__device__ __forceinline__ int ringperm(int d) {
  int a = d ^ ((d & 1) << 11);
  return a ^ (a >> 1);
}

// LDS bank swizzle (T2). HW-verified conflict-free (R7..R19).
__device__ __forceinline__ int swz(int p) { return p ^ ((p >> 6) & 31); }

// Pure 64x64 transpose in 2112 floats via 32x32 BLOCK decomposition.
// Phase 0: diagonal blocks A (lanes<32, regs k<16) and D (lanes>=32, k>=16),
//          each stride-33-padded in its own 1056-float sub-buffer.
// Phase 1: off-diagonal swap B (lanes<32 dump k>=16 -> dest lanes>=32) and
//          C (lanes>=32 dump k<16 -> dest lanes<32).
// Every lane's refilled reg set == its dumped set per phase (closure):
// NO cndmask routing, NO temps, compile-time reg indices per branch.
// All DS ops: fixed j, lane varies -> (lane +- const)&31 distinct banks.
__device__ __forceinline__ void transpose_2phase(v2f (&amp)[32], float* st,
                                                 int lane) {
  // ---- phase 0: diagonal blocks ----
  __syncthreads();
  if (lane < 32) {
#pragma unroll
    for (int k = 0; k < 16; ++k) {
      st[lane * 33 + 2 * k]     = amp[k].x;
      st[lane * 33 + 2 * k + 1] = amp[k].y;
    }
  } else {
#pragma unroll
    for (int k = 16; k < 32; ++k) {
      st[1056 + (lane - 32) * 33 + 2 * (k - 16)]     = amp[k].x;
      st[1056 + (lane - 32) * 33 + 2 * (k - 16) + 1] = amp[k].y;
    }
  }
  __syncthreads();
  if (lane < 32) {
#pragma unroll
    for (int k = 0; k < 16; ++k) {
      amp[k].x = st[(2 * k) * 33 + lane];
      amp[k].y = st[(2 * k + 1) * 33 + lane];
    }
  } else {
#pragma unroll
    for (int k = 16; k < 32; ++k) {
      amp[k].x = st[1056 + (2 * k - 32) * 33 + (lane - 32)];
      amp[k].y = st[1056 + (2 * k - 31) * 33 + (lane - 32)];
    }
  }
  // ---- phase 1: off-diagonal swap (B -> [0,1056), C -> [1056,2112)) ----
  __syncthreads();
  if (lane < 32) {
#pragma unroll
    for (int k = 16; k < 32; ++k) {              // B: writer (l<32, j>=32)
      st[(2 * k - 32) * 33 + lane] = amp[k].x;   // addr = (j-32)*33 + l
      st[(2 * k - 31) * 33 + lane] = amp[k].y;
    }
  } else {
#pragma unroll
    for (int k = 0; k < 16; ++k) {               // C: writer (l>=32, j<32)
      st[1056 + (2 * k) * 33 + (lane - 32)]     = amp[k].x;  // 1056+j*33+(l-32)
      st[1056 + (2 * k + 1) * 33 + (lane - 32)] = amp[k].y;
    }
  }
  __syncthreads();
  if (lane < 32) {
#pragma unroll
    for (int k = 16; k < 32; ++k) {              // refill from C
      amp[k].x = st[1056 + lane * 33 + (2 * k - 32)];
      amp[k].y = st[1056 + lane * 33 + (2 * k - 31)];
    }
  } else {
#pragma unroll
    for (int k = 0; k < 16; ++k) {               // refill from B
      amp[k].x = st[(lane - 32) * 33 + 2 * k];
      amp[k].y = st[(lane - 32) * 33 + 2 * k + 1];
    }
  }
}

// One wave per batch element; state in 32 packed float2 regs (64 amps/lane).
// R20 = R18/R3 structure (82.7us; VGPR 92, conflicts 0) + LDS 16640 -> 8448 B
// so all 16 blocks/CU co-reside (R3: LDS-capped at 9). R4's regression is
// attributed to VGPR pressure from cndmask routing in its parity split; this
// version's block-transpose split is register-closed (no routing, no temps).
// T2 keeps R4's tag split (addr4^addr11 phases, &2047 compression) which is
// correctness-PROVEN by R4's passing run; bank bits 0..4 untouched by &2047.
// R2 lesson: NO launch_bounds VGPR forcing. R1 lesson: no long-dep trees.
__global__ __launch_bounds__(64) void qsim_kernel(
    const void* __restrict__ x,    // [B,12] f32
    const void* __restrict__ w,    // [2,12] f32
    const void* __restrict__ Wm,   // [2,12] f32
    const void* __restrict__ bv,   // [2]    f32
    void* __restrict__ out)        // [B,2]  f32
{
  __shared__ float st[2112];       // 8448 B
  const int lane = threadIdx.x;
  const int b = blockIdx.x;

  // ---- inline dtype probe (HW-proven R5..R19) ----
  bool f32;
  {
    const unsigned short* xu = (const unsigned short*)x;
    int insane = 0;
#pragma unroll
    for (int i = 0; i < 16; ++i) {
      float v = b2f((unsigned int)xu[2 * i]);
      float a = fabsf(v);
      if (!(a <= 64.f) || (a != 0.f && a < 1e-8f)) ++insane;
    }
    f32 = (insane >= 2);
  }

  // ---- direct init in layout B (layer-1 CNOT perm folded, no LDS; R13+) ----
  v2f amp[32];
  {
    float csx[12], snx[12];
#pragma unroll
    for (int q = 0; q < 12; ++q) {
      float h = 0.5f * ldv(x, b * NQ + q, f32);
      csx[q] = __cosf(h); snx[q] = __sinf(h);
    }
    const int rb = ringperm(lane << 6);
    float f0[12], f1[12];
#pragma unroll
    for (int q = 0; q < 12; ++q) {
      int r = (rb >> (11 - q)) & 1;
      f0[q] = r ? snx[q] : csx[q];
      f1[q] = r ? csx[q] : snx[q];
    }
    const float K   = f0[2] * f0[3] * f0[4] * f0[5];
    const float h0f = f0[0] * f0[1];
    const float h1f = f1[0] * f1[1];
    const float u00 = f0[11] * h0f, u01 = f1[11] * h1f;
    const float u10 = f1[11] * h0f, u11 = f0[11] * h1f;
#pragma unroll
    for (int j5 = 0; j5 < 2; ++j5) {
      const float a5 = K * (j5 ? f1[6] : f0[6]);
#pragma unroll
      for (int j4 = 0; j4 < 2; ++j4) {
        const float a4 = a5 * ((j4 ^ j5) ? f1[7] : f0[7]);
#pragma unroll
        for (int j3 = 0; j3 < 2; ++j3) {
          const float a3 = a4 * ((j3 ^ j4) ? f1[8] : f0[8]);
#pragma unroll
          for (int j2 = 0; j2 < 2; ++j2) {
            const float a2 = a3 * ((j2 ^ j3) ? f1[9] : f0[9]);
#pragma unroll
            for (int j1 = 0; j1 < 2; ++j1) {
              const float a1 = a2 * ((j1 ^ j2) ? f1[10] : f0[10]);
              const int k = (j5 << 4) | (j4 << 3) | (j3 << 2) | (j2 << 1) | j1;
              amp[k].x = a1 * (j1 ? u10 : u00);
              amp[k].y = a1 * (j1 ? u11 : u01);
            }
          }
        }
      }
    }
  }

  const int rb1 = swz(ringperm(lane << 6));      // T2 read base (full)
  const int rbc = rb1 & 2047;                    // T2 read base (compressed)
  const bool l4 = (lane & 16) != 0;

  // ================= layer 1: RY gates (3-shear form; R15+) ================
#pragma unroll
  for (int q = 6; q < 11; ++q) {
    float h = 0.5f * ldv(w, 0 * NQ + q, f32);
    const float t = __tanf(0.5f * h), s = __sinf(h);
    const int hm = 1 << (10 - q);
#pragma unroll
    for (int k = 0; k < 32; ++k) {
      if (k & hm) continue;
      amp[k]      += -t * amp[k | hm];
      amp[k | hm] +=  s * amp[k];
      amp[k]      += -t * amp[k | hm];
    }
  }
  {
    float h = 0.5f * ldv(w, 0 * NQ + 11, f32);
    const float t = __tanf(0.5f * h), s = __sinf(h);
#pragma unroll
    for (int k = 0; k < 32; ++k) {
      amp[k].x = fmaf(-t, amp[k].y, amp[k].x);
      amp[k].y = fmaf( s, amp[k].x, amp[k].y);
      amp[k].x = fmaf(-t, amp[k].y, amp[k].x);
    }
  }

  // ---- T1: pure transpose B -> A (block 2-phase, 2112 floats) ----
  transpose_2phase(amp, st, lane);

  // ---- q0..4 packed (layout A), q5 in-element (R15+) ----
#pragma unroll
  for (int q = 0; q < 5; ++q) {
    float h = 0.5f * ldv(w, 0 * NQ + q, f32);
    const float t = __tanf(0.5f * h), s = __sinf(h);
    const int hm = 1 << (4 - q);
#pragma unroll
    for (int k = 0; k < 32; ++k) {
      if (k & hm) continue;
      amp[k]      += -t * amp[k | hm];
      amp[k | hm] +=  s * amp[k];
      amp[k]      += -t * amp[k | hm];
    }
  }
  {
    float h = 0.5f * ldv(w, 0 * NQ + 5, f32);
    const float t = __tanf(0.5f * h), s = __sinf(h);
#pragma unroll
    for (int k = 0; k < 32; ++k) {
      amp[k].x = fmaf(-t, amp[k].y, amp[k].x);
      amp[k].y = fmaf( s, amp[k].x, amp[k].y);
      amp[k].x = fmaf(-t, amp[k].y, amp[k].x);
    }
  }

  // ================= layer 2: CNOT perm only; RYs folded ===================
  // ---- T2: ring-perm transpose A -> B, tag addr4^addr11, 2-phase, &2047 ----
  // (R4-verbatim; correctness proven by R4's passing run.)
  __syncthreads();
  if (!l4) {
#pragma unroll
    for (int j = 0; j < 64; ++j) {
      if (((j >> 4) ^ (j >> 5)) & 1) continue;               // keep j4^j5==0
      st[(((j << 6) ^ (j & 31)) & 2047) ^ lane] = amp[j >> 1][j & 1];
    }
  } else {
#pragma unroll
    for (int j = 0; j < 64; ++j) {
      if (!((((j >> 4) ^ (j >> 5)) & 1))) continue;          // keep j4^j5==1
      st[(((j << 6) ^ (j & 31)) & 2047) ^ lane] = amp[j >> 1][j & 1];
    }
  }
  __syncthreads();
  if (!l4) {
#pragma unroll
    for (int j = 0; j < 64; ++j) {
      if (((j >> 4) ^ (j >> 5)) & 1) continue;
      amp[j >> 1][j & 1] = st[rbc ^ (swz(ringperm(j)) & 2047)];
    }
  } else {
#pragma unroll
    for (int j = 0; j < 64; ++j) {
      if (!((((j >> 4) ^ (j >> 5)) & 1))) continue;
      amp[j >> 1][j & 1] = st[rbc ^ (swz(ringperm(j)) & 2047)];
    }
  }
  // phase 1: complement j-sets
  __syncthreads();
  if (!l4) {
#pragma unroll
    for (int j = 0; j < 64; ++j) {
      if (!((((j >> 4) ^ (j >> 5)) & 1))) continue;
      st[(((j << 6) ^ (j & 31)) & 2047) ^ lane] = amp[j >> 1][j & 1];
    }
  } else {
#pragma unroll
    for (int j = 0; j < 64; ++j) {
      if (((j >> 4) ^ (j >> 5)) & 1) continue;
      st[(((j << 6) ^ (j & 31)) & 2047) ^ lane] = amp[j >> 1][j & 1];
    }
  }
  __syncthreads();
  if (!l4) {
#pragma unroll
    for (int j = 0; j < 64; ++j) {
      if (!((((j >> 4) ^ (j >> 5)) & 1))) continue;
      amp[j >> 1][j & 1] = st[rbc ^ (swz(ringperm(j)) & 2047)];
    }
  } else {
#pragma unroll
    for (int j = 0; j < 64; ++j) {
      if (((j >> 4) ^ (j >> 5)) & 1) continue;
      amp[j >> 1][j & 1] = st[rbc ^ (swz(ringperm(j)) & 2047)];
    }
  }

  // ---- <X_q> partials, q6..11 (register-local in B; halved pairs; R16+) ----
  float xB6, xB7, xB8, xB9, xB10, xB11;
  {
    v2f a6 = {0.f, 0.f}, a7 = a6, a8 = a6, a9 = a6, a10 = a6;
    float a11 = 0.f;
#pragma unroll
    for (int k = 0; k < 32; ++k) {
      if (!(k & 16)) a6  += amp[k] * amp[k | 16];
      if (!(k & 8))  a7  += amp[k] * amp[k | 8];
      if (!(k & 4))  a8  += amp[k] * amp[k | 4];
      if (!(k & 2))  a9  += amp[k] * amp[k | 2];
      if (!(k & 1))  a10 += amp[k] * amp[k | 1];
      a11 += amp[k].x * amp[k].y;
    }
    xB6 = 2.f * (a6.x + a6.y);  xB7 = 2.f * (a7.x + a7.y);
    xB8 = 2.f * (a8.x + a8.y);  xB9 = 2.f * (a9.x + a9.y);
    xB10 = 2.f * (a10.x + a10.y); xB11 = 2.f * a11;
  }

  // ---- T3: pure transpose B -> A (block 2-phase, same helper) ----
  transpose_2phase(amp, st, lane);

  // ---- <X_q> partials, q0..5 (register-local in A; halved pairs; R16+) ----
  float xA0, xA1, xA2, xA3, xA4, xA5;
  {
    v2f a0 = {0.f, 0.f}, a1 = a0, a2 = a0, a3 = a0, a4 = a0;
    float a5 = 0.f;
#pragma unroll
    for (int k = 0; k < 32; ++k) {
      if (!(k & 16)) a0 += amp[k] * amp[k | 16];
      if (!(k & 8))  a1 += amp[k] * amp[k | 8];
      if (!(k & 4))  a2 += amp[k] * amp[k | 4];
      if (!(k & 2))  a3 += amp[k] * amp[k | 2];
      if (!(k & 1))  a4 += amp[k] * amp[k | 1];
      a5 += amp[k].x * amp[k].y;
    }
    xA0 = 2.f * (a0.x + a0.y);  xA1 = 2.f * (a1.x + a1.y);
    xA2 = 2.f * (a2.x + a2.y);  xA3 = 2.f * (a3.x + a3.y);
    xA4 = 2.f * (a4.x + a4.y);  xA5 = 2.f * a5;
  }

  // ---- <Z_q> partials (R16+ flat loop, layout A) ----
  v2f Pv = {0.f, 0.f}, zv0 = Pv, zv1 = Pv, zv2 = Pv, zv3 = Pv, zv4 = Pv;
  float z5 = 0.f;
#pragma unroll
  for (int k = 0; k < 32; ++k) {
    v2f pr = amp[k] * amp[k];
    Pv += pr;
    zv0 += (k & 16) ? -pr : pr;
    zv1 += (k & 8)  ? -pr : pr;
    zv2 += (k & 4)  ? -pr : pr;
    zv3 += (k & 2)  ? -pr : pr;
    zv4 += (k & 1)  ? -pr : pr;
    z5  += pr.x - pr.y;
  }
  const float P  = Pv.x + Pv.y;
  const float z0 = zv0.x + zv0.y, z1 = zv1.x + zv1.y, z2 = zv2.x + zv2.y;
  const float z3 = zv3.x + zv3.y, z4 = zv4.x + zv4.y;

  // ---- layer-2 angles (FULL angle): <Z>_final = ct*Z - st*X (R15+) ----
  float ct[12], sn[12];
#pragma unroll
  for (int q = 0; q < 12; ++q) {
    float th = ldv(w, NQ + q, f32);
    ct[q] = __cosf(th); sn[q] = __sinf(th);
  }
  const float zA[6] = {z0, z1, z2, z3, z4, z5};
  const float xA[6] = {xA0, xA1, xA2, xA3, xA4, xA5};
  const float xB[6] = {xB6, xB7, xB8, xB9, xB10, xB11};

  // ---- fused linear head (R16+ verbatim) ----
  float t0, t1;
#pragma unroll
  for (int r = 0; r < 2; ++r) {
    float acc = 0.f, wsum = 0.f;
#pragma unroll
    for (int q = 0; q < 6; ++q) {
      float wv = ldv(Wm, r * NQ + q, f32);
      acc = fmaf(wv, fmaf(ct[q], zA[q], -sn[q] * xA[q]), acc);
    }
#pragma unroll
    for (int q = 6; q < 12; ++q) {
      float wv = ldv(Wm, r * NQ + q, f32);
      float wc = wv * ct[q];
      wsum += ((lane >> (11 - q)) & 1) ? -wc : wc;
      acc = fmaf(-wv * sn[q], xB[q - 6], acc);
    }
    acc = fmaf(P, wsum, acc);
    if (r == 0) t0 = acc; else t1 = acc;
  }
#pragma unroll
  for (int off = 32; off; off >>= 1) {
    t0 += __shfl_xor(t0, off, 64);
    t1 += __shfl_xor(t1, off, 64);
  }
  if (lane < 2) {
    float o = ((lane == 0) ? t0 : t1) + ldv(bv, lane, f32);
    if (f32) ((float*)out)[b * 2 + lane] = o;
    else     ((bf16*)out)[b * 2 + lane] = __float2bfloat16(o);
  }
}

extern "C" void kernel_launch(void* const* d_in, const int* in_sizes, int n_in,
                              void* d_out, int out_size, void* d_ws, size_t ws_size,
                              hipStream_t stream) {
  const void* x  = d_in[0];
  const void* w  = d_in[1];
  const void* Wm = d_in[2];
  const void* bv = d_in[3];
  const int batch = out_size / 2;   // out is [B, 2]
  qsim_kernel<<<dim3(batch), dim3(64), 0, stream>>>(x, w, Wm, bv, d_out);
}

// Round 6
// 83.502 us; speedup vs baseline: 3.4402x; 3.4402x over previous
//
#include <hip/hip_runtime.h>
#include <hip/hip_bf16.h>

#define NQ 12
typedef __hip_bfloat16 bf16;
typedef float v2f __attribute__((ext_vector_type(2)));

__device__ __forceinline__ float b2f(unsigned int u) {
  union { unsigned int i; float f; } v; v.i = u << 16; return v.f;
}

// Dtype-adaptive scalar load (world: f32 — probe-verified on HW R5..R20).
__device__ __forceinline__ float ldv(const void* p, int i, bool f32) {
  if (f32) return ((const float*)p)[i];
  return b2f((unsigned int)((const unsigned short*)p)[i]);
}

// Composite permutation of the 12 sequential ring CNOTs. HW-verified (R2..R20).
__device__ __forceinline__ int ringperm(int d) {
  int a = d ^ ((d & 1) << 11);
  return a ^ (a >> 1);
}

// LDS bank swizzle (T2). HW-verified conflict-free (R7..R20).
__device__ __forceinline__ int swz(int p) { return p ^ ((p >> 6) & 31); }

// One wave per batch element; state in 32 packed float2 regs (64 amps/lane).
// R21 = R18/R3 verbatim (proven 82.7us; VGPR 92, LDS 16896, conflicts 0)
// MINUS all 6 __syncthreads(). Blocks are SINGLE-WAVE: LDS ops of one wave
// are processed in order by the DS pipe (LLVM models DS as in-order; the
// wave-private LDS scratch idiom), so writes are visible to later reads of
// the same wave with NO barrier and NO full lgkmcnt(0) drain. Each removed
// barrier was s_waitcnt vmcnt(0) lgkmcnt(0) + s_barrier = a full DS-queue
// drain serializing write-phase against read-phase. Removal-only change:
// zero new instructions, zero register-pressure risk, identical addressing.
// R5 lesson: no array-by-reference helpers (SROA failure -> scratch).
// R2 lesson: no launch_bounds VGPR forcing. R1 lesson: no long-dep trees.
__global__ __launch_bounds__(64) void qsim_kernel(
    const void* __restrict__ x,    // [B,12] f32
    const void* __restrict__ w,    // [2,12] f32
    const void* __restrict__ Wm,   // [2,12] f32
    const void* __restrict__ bv,   // [2]    f32
    void* __restrict__ out)        // [B,2]  f32
{
  __shared__ float st[4160];       // 64 rows x stride 65 (T1/T3); T2 uses <4096
  const int lane = threadIdx.x;
  const int b = blockIdx.x;

  // ---- inline dtype probe (HW-proven R5..R20) ----
  bool f32;
  {
    const unsigned short* xu = (const unsigned short*)x;
    int insane = 0;
#pragma unroll
    for (int i = 0; i < 16; ++i) {
      float v = b2f((unsigned int)xu[2 * i]);
      float a = fabsf(v);
      if (!(a <= 64.f) || (a != 0.f && a < 1e-8f)) ++insane;
    }
    f32 = (insane >= 2);
  }

  // ---- direct init in layout B (layer-1 CNOT perm folded, no LDS; R13+) ----
  v2f amp[32];
  {
    float csx[12], snx[12];
#pragma unroll
    for (int q = 0; q < 12; ++q) {
      float h = 0.5f * ldv(x, b * NQ + q, f32);
      csx[q] = __cosf(h); snx[q] = __sinf(h);
    }
    const int rb = ringperm(lane << 6);
    float f0[12], f1[12];
#pragma unroll
    for (int q = 0; q < 12; ++q) {
      int r = (rb >> (11 - q)) & 1;
      f0[q] = r ? snx[q] : csx[q];
      f1[q] = r ? csx[q] : snx[q];
    }
    const float K   = f0[2] * f0[3] * f0[4] * f0[5];
    const float h0f = f0[0] * f0[1];
    const float h1f = f1[0] * f1[1];
    const float u00 = f0[11] * h0f, u01 = f1[11] * h1f;
    const float u10 = f1[11] * h0f, u11 = f0[11] * h1f;
#pragma unroll
    for (int j5 = 0; j5 < 2; ++j5) {
      const float a5 = K * (j5 ? f1[6] : f0[6]);
#pragma unroll
      for (int j4 = 0; j4 < 2; ++j4) {
        const float a4 = a5 * ((j4 ^ j5) ? f1[7] : f0[7]);
#pragma unroll
        for (int j3 = 0; j3 < 2; ++j3) {
          const float a3 = a4 * ((j3 ^ j4) ? f1[8] : f0[8]);
#pragma unroll
          for (int j2 = 0; j2 < 2; ++j2) {
            const float a2 = a3 * ((j2 ^ j3) ? f1[9] : f0[9]);
#pragma unroll
            for (int j1 = 0; j1 < 2; ++j1) {
              const float a1 = a2 * ((j1 ^ j2) ? f1[10] : f0[10]);
              const int k = (j5 << 4) | (j4 << 3) | (j3 << 2) | (j2 << 1) | j1;
              amp[k].x = a1 * (j1 ? u10 : u00);
              amp[k].y = a1 * (j1 ? u11 : u01);
            }
          }
        }
      }
    }
  }

  const int rb1 = swz(ringperm(lane << 6));      // T2 read base
  const int wpad = lane * 65;                    // padded write base (T1/T3)

  // ================= layer 1: RY gates (3-shear form; R15+) ================
#pragma unroll
  for (int q = 6; q < 11; ++q) {
    float h = 0.5f * ldv(w, 0 * NQ + q, f32);
    const float t = __tanf(0.5f * h), s = __sinf(h);
    const int hm = 1 << (10 - q);
#pragma unroll
    for (int k = 0; k < 32; ++k) {
      if (k & hm) continue;
      amp[k]      += -t * amp[k | hm];
      amp[k | hm] +=  s * amp[k];
      amp[k]      += -t * amp[k | hm];
    }
  }
  {
    float h = 0.5f * ldv(w, 0 * NQ + 11, f32);
    const float t = __tanf(0.5f * h), s = __sinf(h);
#pragma unroll
    for (int k = 0; k < 32; ++k) {
      amp[k].x = fmaf(-t, amp[k].y, amp[k].x);
      amp[k].y = fmaf( s, amp[k].x, amp[k].y);
      amp[k].x = fmaf(-t, amp[k].y, amp[k].x);
    }
  }

  // ---- T1: pure transpose B -> A, padded stride-65; NO barriers ----
  // (single-wave block: DS pipe is in-order, write->read visible w/o drain)
#pragma unroll
  for (int j = 0; j < 64; ++j)
    st[wpad + j] = amp[j >> 1][j & 1];
#pragma unroll
  for (int j = 0; j < 64; ++j)
    amp[j >> 1][j & 1] = st[j * 65 + lane];

  // ---- q0..4 packed (layout A), q5 in-element (R15+) ----
#pragma unroll
  for (int q = 0; q < 5; ++q) {
    float h = 0.5f * ldv(w, 0 * NQ + q, f32);
    const float t = __tanf(0.5f * h), s = __sinf(h);
    const int hm = 1 << (4 - q);
#pragma unroll
    for (int k = 0; k < 32; ++k) {
      if (k & hm) continue;
      amp[k]      += -t * amp[k | hm];
      amp[k | hm] +=  s * amp[k];
      amp[k]      += -t * amp[k | hm];
    }
  }
  {
    float h = 0.5f * ldv(w, 0 * NQ + 5, f32);
    const float t = __tanf(0.5f * h), s = __sinf(h);
#pragma unroll
    for (int k = 0; k < 32; ++k) {
      amp[k].x = fmaf(-t, amp[k].y, amp[k].x);
      amp[k].y = fmaf( s, amp[k].x, amp[k].y);
      amp[k].x = fmaf(-t, amp[k].y, amp[k].x);
    }
  }

  // ================= layer 2: CNOT perm only; RYs folded ===================
  // ---- T2: ring-CNOT perm + transpose A -> B (XOR layout); NO barriers ----
#pragma unroll
  for (int j = 0; j < 64; ++j)
    st[((j << 6) ^ (j & 31)) ^ lane] = amp[j >> 1][j & 1];
#pragma unroll
  for (int j = 0; j < 64; ++j)
    amp[j >> 1][j & 1] = st[rb1 ^ swz(ringperm(j))];

  // ---- <X_q> partials, q6..11 (register-local in B; halved pairs; R16+) ----
  float xB6, xB7, xB8, xB9, xB10, xB11;
  {
    v2f a6 = {0.f, 0.f}, a7 = a6, a8 = a6, a9 = a6, a10 = a6;
    float a11 = 0.f;
#pragma unroll
    for (int k = 0; k < 32; ++k) {
      if (!(k & 16)) a6  += amp[k] * amp[k | 16];
      if (!(k & 8))  a7  += amp[k] * amp[k | 8];
      if (!(k & 4))  a8  += amp[k] * amp[k | 4];
      if (!(k & 2))  a9  += amp[k] * amp[k | 2];
      if (!(k & 1))  a10 += amp[k] * amp[k | 1];
      a11 += amp[k].x * amp[k].y;
    }
    xB6 = 2.f * (a6.x + a6.y);  xB7 = 2.f * (a7.x + a7.y);
    xB8 = 2.f * (a8.x + a8.y);  xB9 = 2.f * (a9.x + a9.y);
    xB10 = 2.f * (a10.x + a10.y); xB11 = 2.f * a11;
  }

  // ---- T3: pure transpose B -> A, padded stride-65; NO barriers ----
#pragma unroll
  for (int j = 0; j < 64; ++j)
    st[wpad + j] = amp[j >> 1][j & 1];
#pragma unroll
  for (int j = 0; j < 64; ++j)
    amp[j >> 1][j & 1] = st[j * 65 + lane];

  // ---- <X_q> partials, q0..5 (register-local in A; halved pairs; R16+) ----
  float xA0, xA1, xA2, xA3, xA4, xA5;
  {
    v2f a0 = {0.f, 0.f}, a1 = a0, a2 = a0, a3 = a0, a4 = a0;
    float a5 = 0.f;
#pragma unroll
    for (int k = 0; k < 32; ++k) {
      if (!(k & 16)) a0 += amp[k] * amp[k | 16];
      if (!(k & 8))  a1 += amp[k] * amp[k | 8];
      if (!(k & 4))  a2 += amp[k] * amp[k | 4];
      if (!(k & 2))  a3 += amp[k] * amp[k | 2];
      if (!(k & 1))  a4 += amp[k] * amp[k | 1];
      a5 += amp[k].x * amp[k].y;
    }
    xA0 = 2.f * (a0.x + a0.y);  xA1 = 2.f * (a1.x + a1.y);
    xA2 = 2.f * (a2.x + a2.y);  xA3 = 2.f * (a3.x + a3.y);
    xA4 = 2.f * (a4.x + a4.y);  xA5 = 2.f * a5;
  }

  // ---- <Z_q> partials (R16+ flat loop, layout A) ----
  v2f Pv = {0.f, 0.f}, zv0 = Pv, zv1 = Pv, zv2 = Pv, zv3 = Pv, zv4 = Pv;
  float z5 = 0.f;
#pragma unroll
  for (int k = 0; k < 32; ++k) {
    v2f pr = amp[k] * amp[k];
    Pv += pr;
    zv0 += (k & 16) ? -pr : pr;
    zv1 += (k & 8)  ? -pr : pr;
    zv2 += (k & 4)  ? -pr : pr;
    zv3 += (k & 2)  ? -pr : pr;
    zv4 += (k & 1)  ? -pr : pr;
    z5  += pr.x - pr.y;
  }
  const float P  = Pv.x + Pv.y;
  const float z0 = zv0.x + zv0.y, z1 = zv1.x + zv1.y, z2 = zv2.x + zv2.y;
  const float z3 = zv3.x + zv3.y, z4 = zv4.x + zv4.y;

  // ---- layer-2 angles (FULL angle): <Z>_final = ct*Z - st*X (R15+) ----
  float ct[12], sn[12];
#pragma unroll
  for (int q = 0; q < 12; ++q) {
    float th = ldv(w, NQ + q, f32);
    ct[q] = __cosf(th); sn[q] = __sinf(th);
  }
  const float zA[6] = {z0, z1, z2, z3, z4, z5};
  const float xA[6] = {xA0, xA1, xA2, xA3, xA4, xA5};
  const float xB[6] = {xB6, xB7, xB8, xB9, xB10, xB11};

  // ---- fused linear head (R16+ verbatim) ----
  float t0, t1;
#pragma unroll
  for (int r = 0; r < 2; ++r) {
    float acc = 0.f, wsum = 0.f;
#pragma unroll
    for (int q = 0; q < 6; ++q) {
      float wv = ldv(Wm, r * NQ + q, f32);
      acc = fmaf(wv, fmaf(ct[q], zA[q], -sn[q] * xA[q]), acc);
    }
#pragma unroll
    for (int q = 6; q < 12; ++q) {
      float wv = ldv(Wm, r * NQ + q, f32);
      float wc = wv * ct[q];
      wsum += ((lane >> (11 - q)) & 1) ? -wc : wc;
      acc = fmaf(-wv * sn[q], xB[q - 6], acc);
    }
    acc = fmaf(P, wsum, acc);
    if (r == 0) t0 = acc; else t1 = acc;
  }
#pragma unroll
  for (int off = 32; off; off >>= 1) {
    t0 += __shfl_xor(t0, off, 64);
    t1 += __shfl_xor(t1, off, 64);
  }
  if (lane < 2) {
    float o = ((lane == 0) ? t0 : t1) + ldv(bv, lane, f32);
    if (f32) ((float*)out)[b * 2 + lane] = o;
    else     ((bf16*)out)[b * 2 + lane] = __float2bfloat16(o);
  }
}

extern "C" void kernel_launch(void* const* d_in, const int* in_sizes, int n_in,
                              void* d_out, int out_size, void* d_ws, size_t ws_size,
                              hipStream_t stream) {
  const void* x  = d_in[0];
  const void* w  = d_in[1];
  const void* Wm = d_in[2];
  const void* bv = d_in[3];
  const int batch = out_size / 2;   // out is [B, 2]
  qsim_kernel<<<dim3(batch), dim3(64), 0, stream>>>(x, w, Wm, bv, d_out);
}